// Round 5
// baseline (2397.844 us; speedup 1.0000x reference)
//
#include <hip/hip_runtime.h>
#include <math.h>

#define N_PTS 8192
#define M_PTS 2048
#define NM_PTS 10240
#define D_DIM 768
#define EPS_F 0.0025f
#define INV_EPS_F 400.0f
#define SINK_ITERS 50
#define QSCALE_F 12800.0f     // u16 units: (C/eps)*32  (step 1/32 nat)
#define U16_TO_NAT 0.03125f
#define LOG2E_F 1.4426950408889634f
#define LN2_F   0.6931471805599453f
#define R8_STEP2_F 0.5410106403333613f   // 0.375 nat * log2(e): u8 step in log2 units

typedef __attribute__((ext_vector_type(8))) short short8;
typedef __attribute__((ext_vector_type(4))) float f32x4;

// Layout note: Q8 / QT8 rows are stored PERMUTED per 2048-col segment:
// byte position p = 32L + 4t + e  (L=0..63, t=0..7, e=0..3) holds the
// residual of logical column c = 256t + 4L + e. Lane L of a wave reads
// bytes [32L..32L+31] (two uint4) and the matching bias floats with
// hb4[64t + lane] -> fully coalesced.
//
// Round-10: persistent v3. Evidence: softmin loop is pinned at the
// ~7 us/dispatch kernel-boundary floor (r6/r9: -30% VALU and -50% wgs both
// moved it ~0). r7 failed on L2-flush storms, r8 on SERIALIZED scalar sc1
// staging + hot polling. v3 fixes exactly those: (a) batched staging --
// issue all sc1 loads into registers, then write LDS (one latency
// exposure); (b) 256x1024 blocks (half the staging volume of r8);
// (c) two-level barrier with spread counters and s_sleep(8) cold polls.
// Structure/arithmetic identical to the twice-validated r7/r8 kernel.

// ---------------------------------------------------------------------------
__device__ __forceinline__ unsigned short sk_f2bf(float f)
{
    const unsigned u = __float_as_uint(f);
    return (unsigned short)((u + 0x7fffu + ((u >> 16) & 1u)) >> 16);
}

__device__ __forceinline__ float sk_ld_agent(const float* p)
{
    return __hip_atomic_load(p, __ATOMIC_RELAXED, __HIP_MEMORY_SCOPE_AGENT);
}
__device__ __forceinline__ void sk_st_agent(float* p, float v)
{
    __hip_atomic_store(p, v, __ATOMIC_RELAXED, __HIP_MEMORY_SCOPE_AGENT);
}

// unpack 4 bytes of w into z[o..o+3] = hbr - byte*step2   (log2 units)
__device__ __forceinline__ void sk_z4(unsigned int w, const float* hbr, int o, float* z)
{
    z[o + 0] = fmaf((float)(w & 0xffu),         -R8_STEP2_F, hbr[o + 0]);
    z[o + 1] = fmaf((float)((w >> 8) & 0xffu),  -R8_STEP2_F, hbr[o + 1]);
    z[o + 2] = fmaf((float)((w >> 16) & 0xffu), -R8_STEP2_F, hbr[o + 2]);
    z[o + 3] = fmaf((float)(w >> 24),           -R8_STEP2_F, hbr[o + 3]);
}

// wave-wide (m, s) in log2 domain over 64 lanes x 32 elements.
__device__ __forceinline__ void sk_wave_ms(
    const uint4 q0, const uint4 q1, const float* hbr, float& mo, float& so)
{
    float z[32];
    sk_z4(q0.x, hbr, 0, z);  sk_z4(q0.y, hbr, 4, z);
    sk_z4(q0.z, hbr, 8, z);  sk_z4(q0.w, hbr, 12, z);
    sk_z4(q1.x, hbr, 16, z); sk_z4(q1.y, hbr, 20, z);
    sk_z4(q1.z, hbr, 24, z); sk_z4(q1.w, hbr, 28, z);
    float m0 = z[0], m1 = z[1], m2 = z[2], m3 = z[3];
    #pragma unroll
    for (int k = 4; k < 32; k += 4) {
        m0 = fmaxf(m0, z[k + 0]); m1 = fmaxf(m1, z[k + 1]);
        m2 = fmaxf(m2, z[k + 2]); m3 = fmaxf(m3, z[k + 3]);
    }
    float m = fmaxf(fmaxf(m0, m1), fmaxf(m2, m3));
    #pragma unroll
    for (int off = 1; off < 64; off <<= 1)
        m = fmaxf(m, __shfl_xor(m, off, 64));
    float s0 = 0.f, s1 = 0.f, s2 = 0.f, s3 = 0.f;
    #pragma unroll
    for (int k = 0; k < 32; k += 4) {
        s0 += __builtin_amdgcn_exp2f(z[k + 0] - m);
        s1 += __builtin_amdgcn_exp2f(z[k + 1] - m);
        s2 += __builtin_amdgcn_exp2f(z[k + 2] - m);
        s3 += __builtin_amdgcn_exp2f(z[k + 3] - m);
    }
    float s = (s0 + s1) + (s2 + s3);
    #pragma unroll
    for (int off = 1; off < 64; off <<= 1)
        s += __shfl_xor(s, off, 64);
    mo = m; so = s;
}

// ---------------------------------------------------------------------------
// Two-level grid barrier for 256 blocks: 32 groups x 8 blocks. Monotonic
// counters (no resets). Arrive counters 128 B apart; release fans out to 32
// group flags (<=8 pollers/line); cold poll via s_sleep(8) (~700 ns cycle).
// All accesses agent-scope atomics (bypass non-coherent L2); a wave's own
// sc1 data stores are ordered before arrival by the vmcnt(0).
// ---------------------------------------------------------------------------
__device__ __forceinline__ void sk_gbar(int* __restrict__ bar, int target)
{
    asm volatile("s_waitcnt vmcnt(0)" ::: "memory");
    __syncthreads();
    if (threadIdx.x == 0) {
        const int g = blockIdx.x & 31;
        int* grp  = bar + g * 32;
        int* flag = bar + g * 32 + 16;
        int* root = bar + 1024;
        if (__hip_atomic_fetch_add(grp, 1, __ATOMIC_RELAXED,
                                   __HIP_MEMORY_SCOPE_AGENT) == target * 8 - 1) {
            if (__hip_atomic_fetch_add(root, 1, __ATOMIC_RELAXED,
                                       __HIP_MEMORY_SCOPE_AGENT) == target * 32 - 1) {
                #pragma unroll
                for (int g2 = 0; g2 < 32; ++g2)
                    __hip_atomic_store(bar + g2 * 32 + 16, target,
                                       __ATOMIC_RELAXED, __HIP_MEMORY_SCOPE_AGENT);
            }
        }
        while (__hip_atomic_load(flag, __ATOMIC_RELAXED,
                                 __HIP_MEMORY_SCOPE_AGENT) < target)
            __builtin_amdgcn_s_sleep(8);
    }
    __syncthreads();
}

// ---------------------------------------------------------------------------
// init: LW = (log2 h | log2 hi), hbF = log2 hi (g=0), R32 = INT_MAX, bar = 0
// ---------------------------------------------------------------------------
__global__ __launch_bounds__(256) void sk_init(
    const float* __restrict__ h, const float* __restrict__ hi,
    float* __restrict__ lw, float* __restrict__ hbF, int* __restrict__ r32,
    int* __restrict__ bar)
{
    const int t = blockIdx.x * 256 + threadIdx.x;
    if (t < N_PTS) { lw[t] = __log2f(h[t]); r32[t] = 0x7fffffff; }
    else if (t < NM_PTS) {
        const float v = __log2f(hi[t - N_PTS]);
        lw[t] = v; hbF[t - N_PTS] = v;
    }
    if (t < 2048) bar[t] = 0;
}

// ---------------------------------------------------------------------------
__global__ __launch_bounds__(256) void sk_cast(
    const float* __restrict__ src, unsigned short* __restrict__ dst)
{
    const int t = blockIdx.x * 256 + threadIdx.x;
    const float4 v = ((const float4*)src)[t];
    ushort4 o;
    o.x = sk_f2bf(v.x); o.y = sk_f2bf(v.y); o.z = sk_f2bf(v.z); o.w = sk_f2bf(v.w);
    ((ushort4*)dst)[t] = o;
}

// ---------------------------------------------------------------------------
// MFMA bf16 NT-GEMM, 128x128 tile, 256 thr, k+1 register prefetch.
// ---------------------------------------------------------------------------
template<int MODE>
__global__ __launch_bounds__(256) void sk_mfma(
    const unsigned short* __restrict__ A, const unsigned short* __restrict__ B,
    unsigned short* __restrict__ Xb,
    unsigned short* __restrict__ QT, int* __restrict__ R32,
    const float* __restrict__ xs, const float* __restrict__ ys)
{
    constexpr int LS = 40;
    __shared__ unsigned short As[128 * LS];
    __shared__ unsigned short Bs[128 * LS];
    __shared__ int rmin[128];
    const int tid  = threadIdx.x;
    const int wave = tid >> 6, lane = tid & 63;
    const int quad = lane >> 4, l16 = lane & 15;
    const int row0 = blockIdx.y * 128, col0 = blockIdx.x * 128;
    const int wr = (wave >> 1) * 64, wc = (wave & 1) * 64;
    if (MODE == 1 && tid < 128) rmin[tid] = 0x7fffffff;

    const int sr = tid >> 2;
    const int sk = (tid & 3) * 8;
    const unsigned short* Ap  = A + (size_t)(row0 + sr) * D_DIM + sk;
    const unsigned short* Ap2 = Ap + (size_t)64 * D_DIM;
    const unsigned short* Bp  = B + (size_t)(col0 + sr) * D_DIM + sk;
    const unsigned short* Bp2 = Bp + (size_t)64 * D_DIM;

    f32x4 acc[4][4] = {};

    short8 a0 = *(const short8*)(Ap);
    short8 a1 = *(const short8*)(Ap2);
    short8 b0 = *(const short8*)(Bp);
    short8 b1 = *(const short8*)(Bp2);

    for (int k0 = 0; k0 < D_DIM; k0 += 32) {
        __syncthreads();
        *(short8*)(As + sr * LS + sk)        = a0;
        *(short8*)(As + (sr + 64) * LS + sk) = a1;
        *(short8*)(Bs + sr * LS + sk)        = b0;
        *(short8*)(Bs + (sr + 64) * LS + sk) = b1;
        const int kn = (k0 + 32 < D_DIM) ? k0 + 32 : 0;  // last iter: dummy (hot)
        a0 = *(const short8*)(Ap + kn);
        a1 = *(const short8*)(Ap2 + kn);
        b0 = *(const short8*)(Bp + kn);
        b1 = *(const short8*)(Bp2 + kn);
        __syncthreads();
        short8 af[4], bfr[4];
        #pragma unroll
        for (int i = 0; i < 4; ++i) {
            af[i]  = *(const short8*)(As + (wr + i * 16 + l16) * LS + quad * 8);
            bfr[i] = *(const short8*)(Bs + (wc + i * 16 + l16) * LS + quad * 8);
        }
        #pragma unroll
        for (int i = 0; i < 4; ++i)
            #pragma unroll
            for (int j = 0; j < 4; ++j)
                acc[i][j] = __builtin_amdgcn_mfma_f32_16x16x32_bf16(
                    af[i], bfr[j], acc[i][j], 0, 0, 0);
    }

    if (MODE == 0) {
        unsigned short* sl = As;
        const int sgrp = wr >> 6;
        const int osg = tid >> 7, orow = (tid >> 3) & 15, oc16 = (tid & 7) * 16;
        #pragma unroll
        for (int i = 0; i < 4; ++i) {
            __syncthreads();
            #pragma unroll
            for (int j = 0; j < 4; ++j)
                #pragma unroll
                for (int r = 0; r < 4; ++r)
                    sl[sgrp * 2176 + (quad * 4 + r) * 136 + wc + j * 16 + l16] =
                        sk_f2bf(acc[i][j][r]);
            __syncthreads();
            const unsigned short* src = sl + osg * 2176 + orow * 136 + oc16;
            const short8 v0 = *(const short8*)src;
            const short8 v1 = *(const short8*)(src + 8);
            unsigned short* dst = Xb +
                (size_t)(row0 + osg * 64 + i * 16 + orow) * D_DIM + col0 + oc16;
            *(short8*)dst = v0;
            *(short8*)(dst + 8) = v1;
        }
    } else {
        const int gm0 = row0 + wr + quad * 4;
        const int gn0 = col0 + wc + l16;
        #pragma unroll
        for (int i = 0; i < 4; ++i) {
            float xv[4];
            #pragma unroll
            for (int r = 0; r < 4; ++r) xv[r] = xs[gm0 + i * 16 + r];
            int qmn[4] = {0x7fffffff, 0x7fffffff, 0x7fffffff, 0x7fffffff};
            #pragma unroll
            for (int j = 0; j < 4; ++j) {
                const int gn = gn0 + j * 16;
                const float ysv = ys[gn];
                int iq[4];
                #pragma unroll
                for (int r = 0; r < 4; ++r) {
                    const float c = fmaxf(xv[r] + ysv - acc[i][j][r], 0.f);
                    iq[r] = (int)fminf(fmaf(c, QSCALE_F, 0.5f), 65535.f);
                    qmn[r] = min(qmn[r], iq[r]);
                }
                *(ushort4*)(QT + (size_t)gn * N_PTS + gm0 + i * 16) =
                    make_ushort4((unsigned short)iq[0], (unsigned short)iq[1],
                                 (unsigned short)iq[2], (unsigned short)iq[3]);
            }
            #pragma unroll
            for (int r = 0; r < 4; ++r)
                atomicMin(&rmin[wr + i * 16 + quad * 4 + r], qmn[r]);
        }
        __syncthreads();
        if (tid < 128) atomicMin(&R32[row0 + tid], rmin[tid]);
    }
}

// ---------------------------------------------------------------------------
// xs[r] = 0.5*||Xb[r,:]||^2 from bf16
// ---------------------------------------------------------------------------
__global__ __launch_bounds__(256) void sk_row_norms(
    const unsigned short* __restrict__ Xb, float* __restrict__ XS)
{
    const int row  = blockIdx.x * 4 + (threadIdx.x >> 6);
    const int lane = threadIdx.x & 63;
    const unsigned int* p = (const unsigned int*)(Xb + (size_t)row * D_DIM);
    float s = 0.f;
    #pragma unroll
    for (int k = 0; k < 6; ++k) {
        const unsigned int u = p[lane + k * 64];
        const float f0 = __uint_as_float(u << 16);
        const float f1 = __uint_as_float(u & 0xffff0000u);
        s = fmaf(f0, f0, s); s = fmaf(f1, f1, s);
    }
    #pragma unroll
    for (int off = 32; off; off >>= 1) s += __shfl_xor(s, off, 64);
    if (lane == 0) XS[row] = 0.5f * s;
}

// ---------------------------------------------------------------------------
// Fused transpose+quant: QTu16 [2048 x 8192] -> Q8 (PERMUTED rows, i-major)
// AND QT8 (PERMUTED per-seg rows, j-major), reading QTu exactly once.
// ---------------------------------------------------------------------------
__global__ __launch_bounds__(256) void sk_transq(
    const unsigned short* __restrict__ QT, const int* __restrict__ R32,
    unsigned char* __restrict__ Q8, unsigned char* __restrict__ QT8)
{
    __shared__ unsigned short tile[64][72];
    __shared__ int rs[64];
    const int tid = threadIdx.x;
    const int J0 = blockIdx.x * 64;   // logical j (cols of Q8, rows of QT8)
    const int I0 = blockIdx.y * 64;   // i (rows of Q8, cols of QT8)
    const int tj = tid >> 2, ti = (tid & 3) * 16;
    const uint4* src = (const uint4*)(QT + (size_t)(J0 + tj) * N_PTS + I0 + ti);
    const uint4 a = src[0], b = src[1];
    *(uint4*)&tile[tj][ti] = a;
    *(uint4*)&tile[tj][ti + 8] = b;
    if (tid < 64) rs[tid] = R32[I0 + tid];
    __syncthreads();
    {
        const unsigned int qs[8] = {a.x, a.y, a.z, a.w, b.x, b.y, b.z, b.w};
        const int s  = I0 >> 11;
        const int ip = I0 & 2047;
        const int t  = ip >> 8;
        const int L0 = ((ip >> 2) & 63) + (ti >> 2);
        unsigned char* orow = QT8 + (size_t)(J0 + tj) * N_PTS + 2048 * s + 4 * t;
        #pragma unroll
        for (int q = 0; q < 4; ++q) {
            unsigned char ob[4];
            #pragma unroll
            for (int e = 0; e < 4; ++e) {
                const int k = q * 4 + e;
                const int qv = (int)((qs[k >> 1] >> ((k & 1) * 16)) & 0xffffu);
                ob[e] = (unsigned char)fminf(
                    fmaf((float)(qv - rs[ti + k]), 1.0f / 12.0f, 0.5f), 255.f);
            }
            *(unsigned int*)(orow + 32 * (L0 + q)) = *(const unsigned int*)ob;
        }
    }
    {
        const int li = tid >> 2, lj = (tid & 3) * 16;
        const int R = rs[li];
        const int L0 = (J0 >> 2) & 63;      // 16-aligned
        const int t0 = J0 >> 8;
        unsigned char* orow = Q8 + (size_t)(I0 + li) * M_PTS;
        #pragma unroll
        for (int q = 0; q < 4; ++q) {
            unsigned char ob[4];
            #pragma unroll
            for (int e = 0; e < 4; ++e) {
                const int qv = (int)tile[lj + q * 4 + e][li];
                ob[e] = (unsigned char)fminf(
                    fmaf((float)(qv - R), 1.0f / 12.0f, 0.5f), 255.f);
            }
            *(unsigned int*)(orow + 32 * (L0 + (lj >> 2) + q) + 4 * t0) =
                *(const unsigned int*)ob;
        }
    }
}

// ---------------------------------------------------------------------------
// Persistent cooperative Sinkhorn loop v3. 256 blocks x 1024 thr (4096 waves,
// 1 block/CU). Matrix bytes live in registers for all 50 iters. Per phase the
// block stages the bias vector into LDS with BATCHED agent-scope loads (all
// issued, then written -> one latency exposure). Results published with
// agent-scope stores. No cache fences.
// Wave w (0..15): F rows 2*gw, 2*gw+1 (gw = blockIdx*16+w).
//                 G: seg = w&3, rl = w>>2; rows base+rl, base+4+rl (base=blk*8).
// ---------------------------------------------------------------------------
__global__ __launch_bounds__(1024) void sk_sinkhorn_loop(
    const unsigned char* __restrict__ Q8, const unsigned char* __restrict__ QT8,
    float* __restrict__ hbF, float* __restrict__ hbG,
    const float* __restrict__ LW, const int* __restrict__ R32,
    float* __restrict__ FO, int* __restrict__ bar)
{
    __shared__ float bl[8192];          // bias staging (32 KB)
    __shared__ float mred[32], sred[32];
    const int tid = threadIdx.x, wave = tid >> 6, lane = tid & 63;
    const int gw = blockIdx.x * 16 + wave;         // 0..4095
    const int frow0 = gw * 2;

    uint4 qf00, qf01, qf10, qf11;
    {
        const uint4* qp0 = (const uint4*)(Q8 + (size_t)frow0 * M_PTS);
        const uint4* qp1 = (const uint4*)(Q8 + (size_t)(frow0 + 1) * M_PTS);
        qf00 = qp0[lane * 2]; qf01 = qp0[lane * 2 + 1];
        qf10 = qp1[lane * 2]; qf11 = qp1[lane * 2 + 1];
    }
    const int seg = wave & 3, rl = wave >> 2;      // rl 0..3
    const int base = blockIdx.x * 8;
    uint4 qg00, qg01, qg10, qg11;
    {
        const uint4* qp0 = (const uint4*)(QT8 + (size_t)(base + rl) * N_PTS + seg * 2048);
        const uint4* qp1 = (const uint4*)(QT8 + (size_t)(base + 4 + rl) * N_PTS + seg * 2048);
        qg00 = qp0[lane * 2]; qg01 = qp0[lane * 2 + 1];
        qg10 = qp1[lane * 2]; qg11 = qp1[lane * 2 + 1];
    }
    const float4* bl4 = (const float4*)bl;
    float hbr[32];
    int bt = 0;

    for (int it = 0; it < SINK_ITERS; ++it) {
        // ---- stage hbF (2048 f): batched sc1 loads, then LDS writes
        {
            const float v0 = sk_ld_agent(hbF + tid);
            const float v1 = sk_ld_agent(hbF + 1024 + tid);
            bl[tid] = v0; bl[1024 + tid] = v1;
        }
        __syncthreads();
        #pragma unroll
        for (int t = 0; t < 8; ++t) {
            const float4 v = bl4[t * 64 + lane];
            hbr[t * 4 + 0] = v.x; hbr[t * 4 + 1] = v.y;
            hbr[t * 4 + 2] = v.z; hbr[t * 4 + 3] = v.w;
        }
        {
            float m, s;
            sk_wave_ms(qf00, qf01, hbr, m, s);
            if (lane == 0) sk_st_agent(hbG + frow0, LW[frow0] - (m + __log2f(s)));
            sk_wave_ms(qf10, qf11, hbr, m, s);
            if (lane == 0) sk_st_agent(hbG + frow0 + 1,
                                       LW[frow0 + 1] - (m + __log2f(s)));
        }
        sk_gbar(bar, ++bt);
        // ---- stage hbG (8192 f): batched sc1 loads, then LDS writes
        {
            float gv[8];
            #pragma unroll
            for (int k = 0; k < 8; ++k)
                gv[k] = sk_ld_agent(hbG + tid + k * 1024);
            #pragma unroll
            for (int k = 0; k < 8; ++k)
                bl[tid + k * 1024] = gv[k];
        }
        __syncthreads();
        #pragma unroll
        for (int t = 0; t < 8; ++t) {
            const float4 v = bl4[seg * 512 + t * 64 + lane];
            hbr[t * 4 + 0] = v.x; hbr[t * 4 + 1] = v.y;
            hbr[t * 4 + 2] = v.z; hbr[t * 4 + 3] = v.w;
        }
        {
            float m, s;
            sk_wave_ms(qg00, qg01, hbr, m, s);
            if (lane == 0) { mred[wave] = m; sred[wave] = s; }
            sk_wave_ms(qg10, qg11, hbr, m, s);
            if (lane == 0) { mred[16 + wave] = m; sred[16 + wave] = s; }
        }
        __syncthreads();
        if (tid < 8) {
            const int p = tid >> 2, rloc = tid & 3;
            const int b = p * 16 + rloc * 4;
            const float M = fmaxf(fmaxf(mred[b], mred[b + 1]),
                                  fmaxf(mred[b + 2], mred[b + 3]));
            float S = 0.f;
            #pragma unroll
            for (int k = 0; k < 4; ++k)
                S += sred[b + k] * __builtin_amdgcn_exp2f(mred[b + k] - M);
            const int row = base + p * 4 + rloc;
            sk_st_agent(hbF + row, LW[N_PTS + row] - (M + __log2f(S)));
        }
        sk_gbar(bar, ++bt);
    }
    // ---- final differentiable F step -> FO
    {
        const float v0 = sk_ld_agent(hbF + tid);
        const float v1 = sk_ld_agent(hbF + 1024 + tid);
        bl[tid] = v0; bl[1024 + tid] = v1;
    }
    __syncthreads();
    #pragma unroll
    for (int t = 0; t < 8; ++t) {
        const float4 v = bl4[t * 64 + lane];
        hbr[t * 4 + 0] = v.x; hbr[t * 4 + 1] = v.y;
        hbr[t * 4 + 2] = v.z; hbr[t * 4 + 3] = v.w;
    }
    {
        float m, s;
        sk_wave_ms(qf00, qf01, hbr, m, s);
        if (lane == 0)
            FO[frow0] = EPS_F * ((float)R32[frow0] * U16_TO_NAT
                                 - LN2_F * (m + __log2f(s)));
        sk_wave_ms(qf10, qf11, hbr, m, s);
        if (lane == 0)
            FO[frow0 + 1] = EPS_F * ((float)R32[frow0 + 1] * U16_TO_NAT
                                     - LN2_F * (m + __log2f(s)));
    }
}

// ---------------------------------------------------------------------------
// Fallback dispatch-loop kernels (r9-validated; used on coop-launch failure)
// ---------------------------------------------------------------------------
template<bool FINAL>
__global__ __launch_bounds__(512) void sk_smF(
    const unsigned char* __restrict__ Q8, const float* __restrict__ hbF,
    const float* __restrict__ LW, const int* __restrict__ R32,
    float* __restrict__ outv)
{
    const int tid = threadIdx.x, wave = tid >> 6, lane = tid & 63;
    const int frow0 = (blockIdx.x * 8 + wave) * 2;
    const uint4* qp0 = (const uint4*)(Q8 + (size_t)frow0 * M_PTS);
    const uint4* qp1 = (const uint4*)(Q8 + (size_t)(frow0 + 1) * M_PTS);
    const uint4 q00 = qp0[lane * 2], q01 = qp0[lane * 2 + 1];
    const uint4 q10 = qp1[lane * 2], q11 = qp1[lane * 2 + 1];
    float hbr[32];
    const float4* hb4 = (const float4*)hbF;
    #pragma unroll
    for (int t = 0; t < 8; ++t) {
        const float4 v = hb4[t * 64 + lane];
        hbr[t * 4 + 0] = v.x; hbr[t * 4 + 1] = v.y;
        hbr[t * 4 + 2] = v.z; hbr[t * 4 + 3] = v.w;
    }
    float m, s;
    sk_wave_ms(q00, q01, hbr, m, s);
    if (lane == 0) {
        const float lse2 = m + __log2f(s);
        if (FINAL) outv[frow0] = EPS_F * ((float)R32[frow0] * U16_TO_NAT - LN2_F * lse2);
        else       outv[frow0] = LW[frow0] - lse2;
    }
    sk_wave_ms(q10, q11, hbr, m, s);
    if (lane == 0) {
        const float lse2 = m + __log2f(s);
        if (FINAL) outv[frow0 + 1] =
            EPS_F * ((float)R32[frow0 + 1] * U16_TO_NAT - LN2_F * lse2);
        else       outv[frow0 + 1] = LW[frow0 + 1] - lse2;
    }
}

__global__ __launch_bounds__(512) void sk_smG(
    const unsigned char* __restrict__ QT8, const float* __restrict__ hbG,
    const float* __restrict__ LW, float* __restrict__ hbF)
{
    __shared__ float mred[16], sred[16];
    const int tid = threadIdx.x, wave = tid >> 6, lane = tid & 63;
    const int seg = wave & 3, rl = wave >> 2;
    const int base = blockIdx.x * 4;
    const uint4* qp0 = (const uint4*)(QT8 + (size_t)(base + rl) * N_PTS + seg * 2048);
    const uint4* qp1 = (const uint4*)(QT8 + (size_t)(base + 2 + rl) * N_PTS + seg * 2048);
    const uint4 q00 = qp0[lane * 2], q01 = qp0[lane * 2 + 1];
    const uint4 q10 = qp1[lane * 2], q11 = qp1[lane * 2 + 1];
    const float4* hb4 = (const float4*)hbG;
    float hbr[32];
    #pragma unroll
    for (int t = 0; t < 8; ++t) {
        const float4 v = hb4[seg * 512 + t * 64 + lane];
        hbr[t * 4 + 0] = v.x; hbr[t * 4 + 1] = v.y;
        hbr[t * 4 + 2] = v.z; hbr[t * 4 + 3] = v.w;
    }
    float m, s;
    sk_wave_ms(q00, q01, hbr, m, s);
    if (lane == 0) { mred[wave] = m; sred[wave] = s; }
    sk_wave_ms(q10, q11, hbr, m, s);
    if (lane == 0) { mred[8 + wave] = m; sred[8 + wave] = s; }
    __syncthreads();
    if (tid < 4) {
        const int p = tid >> 1, r2 = tid & 1;
        const int b = p * 8 + r2 * 4;
        const float M = fmaxf(fmaxf(mred[b], mred[b + 1]),
                              fmaxf(mred[b + 2], mred[b + 3]));
        float S = 0.f;
        #pragma unroll
        for (int k = 0; k < 4; ++k)
            S += sred[b + k] * __builtin_amdgcn_exp2f(mred[b + k] - M);
        const int row = base + p * 2 + r2;
        hbF[row] = LW[N_PTS + row] - (M + __log2f(S));
    }
}

// ---------------------------------------------------------------------------
// S = <h, FO + eps*ln2*la2/2> + <hi, eps*ln2*(hbF2 - lb2/2)>; out = exp(-S)
// ---------------------------------------------------------------------------
__global__ __launch_bounds__(1024) void sk_finalize(
    const float* __restrict__ fo, const float* __restrict__ hbF,
    const float* __restrict__ h, const float* __restrict__ hi,
    const float* __restrict__ lw, float* __restrict__ out)
{
    const int tid = threadIdx.x;
    float acc = 0.f;
    for (int r = tid; r < N_PTS; r += 1024)
        acc += h[r] * (fo[r] + 0.5f * EPS_F * LN2_F * lw[r]);
    for (int j = tid; j < M_PTS; j += 1024)
        acc += hi[j] * (EPS_F * LN2_F) * (hbF[j] - 0.5f * lw[N_PTS + j]);
    #pragma unroll
    for (int off = 1; off < 64; off <<= 1) acc += __shfl_xor(acc, off, 64);
    __shared__ float red[16];
    if ((tid & 63) == 0) red[tid >> 6] = acc;
    __syncthreads();
    if (tid < 16) {
        float v = red[tid];
        #pragma unroll
        for (int off = 1; off < 16; off <<= 1) v += __shfl_xor(v, off, 16);
        if (tid == 0) out[0] = expf(-v);
    }
}

// ---------------------------------------------------------------------------
extern "C" void kernel_launch(void* const* d_in, const int* in_sizes, int n_in,
                              void* d_out, int out_size, void* d_ws, size_t ws_size,
                              hipStream_t stream)
{
    const float* dpts = (const float*)d_in[0];
    const float* spts = (const float*)d_in[1];
    const float* h    = (const float*)d_in[2];
    const float* hiw  = (const float*)d_in[3];
    const float* W    = (const float*)d_in[4];
    float* out = (float*)d_out;

    float* XS  = (float*)d_ws;                        // NM
    float* LW  = XS + NM_PTS;                         // NM (la2 | lb2), log2 dom
    float* HBF = LW + NM_PTS;                         // M  (log2 dom)
    float* HBG = HBF + M_PTS;                         // N  (log2 dom)
    float* FO  = HBG + N_PTS;                         // N  (nat dom)
    int*   R32 = (int*)(FO + N_PTS);                  // N
    unsigned short* Db = (unsigned short*)(R32 + N_PTS);        // NM x D bf16
    unsigned short* Wb = Db + (size_t)NM_PTS * D_DIM;           // D x D bf16
    unsigned short* Xb = Wb + (size_t)D_DIM * D_DIM;            // NM x D bf16
    unsigned short* QTu = Xb + (size_t)NM_PTS * D_DIM;          // M x N u16
    unsigned char*  Q8  = (unsigned char*)(QTu + (size_t)M_PTS * N_PTS); // N x M u8
    unsigned char*  QT8 = Q8 + (size_t)N_PTS * M_PTS;           // M x N u8
    int*            BAR = (int*)(QT8 + (size_t)M_PTS * N_PTS);  // 2048 ints

    sk_init<<<NM_PTS / 256, 256, 0, stream>>>(h, hiw, LW, HBF, R32, BAR);

    sk_cast<<<(size_t)N_PTS * D_DIM / 1024, 256, 0, stream>>>(dpts, Db);
    sk_cast<<<(size_t)M_PTS * D_DIM / 1024, 256, 0, stream>>>(
        spts, Db + (size_t)N_PTS * D_DIM);
    sk_cast<<<(size_t)D_DIM * D_DIM / 1024, 256, 0, stream>>>(W, Wb);

    sk_mfma<0><<<dim3(D_DIM / 128, NM_PTS / 128), 256, 0, stream>>>(
        Db, Wb, Xb, nullptr, nullptr, nullptr, nullptr);

    sk_row_norms<<<NM_PTS / 4, 256, 0, stream>>>(Xb, XS);

    sk_mfma<1><<<dim3(M_PTS / 128, N_PTS / 128), 256, 0, stream>>>(
        Xb, Xb + (size_t)N_PTS * D_DIM, nullptr, QTu, R32, XS, XS + N_PTS);

    sk_transq<<<dim3(M_PTS / 64, N_PTS / 64), 256, 0, stream>>>(QTu, R32, Q8, QT8);

    {
        const unsigned char* q8c  = Q8;
        const unsigned char* qt8c = QT8;
        const float* lwc = LW;
        const int*   r32c = R32;
        void* kargs[] = { (void*)&q8c, (void*)&qt8c, (void*)&HBF, (void*)&HBG,
                          (void*)&lwc, (void*)&r32c, (void*)&FO, (void*)&BAR };
        hipError_t ce = hipLaunchCooperativeKernel(
            sk_sinkhorn_loop, dim3(256), dim3(1024), kargs, 0u, stream);
        if (ce != hipSuccess) {
            (void)hipGetLastError();   // clear error, fall back to dispatch loop
            for (int it = 0; it < SINK_ITERS; ++it) {
                sk_smF<false><<<N_PTS / 16, 512, 0, stream>>>(Q8, HBF, LW, R32, HBG);
                sk_smG       <<<M_PTS / 4, 512, 0, stream>>>(QT8, HBG, LW, HBF);
            }
            sk_smF<true><<<N_PTS / 16, 512, 0, stream>>>(Q8, HBF, LW, R32, FO);
        }
    }

    sk_finalize<<<1, 1024, 0, stream>>>(FO, HBF, h, hiw, LW, out);
}

// Round 6
// 802.267 us; speedup vs baseline: 2.9888x; 2.9888x over previous
//
#include <hip/hip_runtime.h>
#include <math.h>

#define N_PTS 8192
#define M_PTS 2048
#define NM_PTS 10240
#define D_DIM 768
#define EPS_F 0.0025f
#define INV_EPS_F 400.0f
#define SINK_ITERS 50
#define QSCALE_F 12800.0f     // u16 units: (C/eps)*32  (step 1/32 nat)
#define U16_TO_NAT 0.03125f
#define LOG2E_F 1.4426950408889634f
#define LN2_F   0.6931471805599453f
#define R8_STEP2_F 0.5410106403333613f   // 0.375 nat * log2(e): u8 step in log2 units

typedef __attribute__((ext_vector_type(8))) short short8;
typedef __attribute__((ext_vector_type(4))) float f32x4;

// Layout note: Q8 / QT8 rows are stored PERMUTED per 2048-col segment:
// byte position p = 32L + 4t + e  (L=0..63, t=0..7, e=0..3) holds the
// residual of logical column c = 256t + 4L + e. Lane L of a wave reads
// bytes [32L..32L+31] (two uint4) and the matching bias floats with
// hb4[64t + lane] -> fully coalesced.
//
// Round-11: FINAL STRUCTURE. Persistent/cooperative variants are dead on
// this chip: r7 (threadfence L2-flush storm, 3835 us), r8 (sc1 staging,
// 2650 us), r10 (batched sc1 -- uncoalesced fabric fetch, 2272 us). The
// 101-dispatch loop's ~7 us/dispatch is the hardware floor for a global
// sync + 16 MB matrix re-fetch (L2 is invalidated at every dispatch
// boundary for cross-XCD correctness; bytes come from IF$ at ~2.3 TB/s).
// VALU cuts (-30%) and workgroup cuts (-50%) both moved it ~0: fetch-bound.
// This round restores the r9 dispatch loop (806.8 us) and merges
// init+3 casts into one sk_prep dispatch (saves 3 launch boundaries).

// ---------------------------------------------------------------------------
__device__ __forceinline__ unsigned short sk_f2bf(float f)
{
    const unsigned u = __float_as_uint(f);
    return (unsigned short)((u + 0x7fffu + ((u >> 16) & 1u)) >> 16);
}

// unpack 4 bytes of w into z[o..o+3] = hbr - byte*step2   (log2 units)
__device__ __forceinline__ void sk_z4(unsigned int w, const float* hbr, int o, float* z)
{
    z[o + 0] = fmaf((float)(w & 0xffu),         -R8_STEP2_F, hbr[o + 0]);
    z[o + 1] = fmaf((float)((w >> 8) & 0xffu),  -R8_STEP2_F, hbr[o + 1]);
    z[o + 2] = fmaf((float)((w >> 16) & 0xffu), -R8_STEP2_F, hbr[o + 2]);
    z[o + 3] = fmaf((float)(w >> 24),           -R8_STEP2_F, hbr[o + 3]);
}

// wave-wide (m, s) in log2 domain over 64 lanes x 32 elements.
// Two-phase: wave max first (cheap fmax butterfly), then independent exp2s
// into 4 partial chains, then add butterfly. m, s valid in all lanes.
__device__ __forceinline__ void sk_wave_ms(
    const uint4 q0, const uint4 q1, const float* hbr, float& mo, float& so)
{
    float z[32];
    sk_z4(q0.x, hbr, 0, z);  sk_z4(q0.y, hbr, 4, z);
    sk_z4(q0.z, hbr, 8, z);  sk_z4(q0.w, hbr, 12, z);
    sk_z4(q1.x, hbr, 16, z); sk_z4(q1.y, hbr, 20, z);
    sk_z4(q1.z, hbr, 24, z); sk_z4(q1.w, hbr, 28, z);
    float m0 = z[0], m1 = z[1], m2 = z[2], m3 = z[3];
    #pragma unroll
    for (int k = 4; k < 32; k += 4) {
        m0 = fmaxf(m0, z[k + 0]); m1 = fmaxf(m1, z[k + 1]);
        m2 = fmaxf(m2, z[k + 2]); m3 = fmaxf(m3, z[k + 3]);
    }
    float m = fmaxf(fmaxf(m0, m1), fmaxf(m2, m3));
    #pragma unroll
    for (int off = 1; off < 64; off <<= 1)
        m = fmaxf(m, __shfl_xor(m, off, 64));
    float s0 = 0.f, s1 = 0.f, s2 = 0.f, s3 = 0.f;
    #pragma unroll
    for (int k = 0; k < 32; k += 4) {
        s0 += __builtin_amdgcn_exp2f(z[k + 0] - m);
        s1 += __builtin_amdgcn_exp2f(z[k + 1] - m);
        s2 += __builtin_amdgcn_exp2f(z[k + 2] - m);
        s3 += __builtin_amdgcn_exp2f(z[k + 3] - m);
    }
    float s = (s0 + s1) + (s2 + s3);
    #pragma unroll
    for (int off = 1; off < 64; off <<= 1)
        s += __shfl_xor(s, off, 64);
    mo = m; so = s;
}

// ---------------------------------------------------------------------------
// Merged prep: bf16-cast of dpts|spts (into contiguous Db) and W (into Wb,
// contiguous after Db), PLUS init of LW/HBF/R32 on the first NM_PTS threads.
// Grid: (N*D + M*D + D*D)/4 float4s / 256 = 8256 blocks.
// ---------------------------------------------------------------------------
__global__ __launch_bounds__(256) void sk_prep(
    const float* __restrict__ dpts, const float* __restrict__ spts,
    const float* __restrict__ W,
    const float* __restrict__ h, const float* __restrict__ hi,
    unsigned short* __restrict__ Db,
    float* __restrict__ lw, float* __restrict__ hbF, int* __restrict__ r32)
{
    const int t = blockIdx.x * 256 + threadIdx.x;
    constexpr int N4  = N_PTS * D_DIM / 4;       // 1,572,864
    constexpr int NM4 = NM_PTS * D_DIM / 4;      // 1,966,080
    const float4 v = (t < N4)  ? ((const float4*)dpts)[t]
                   : (t < NM4) ? ((const float4*)spts)[t - N4]
                               : ((const float4*)W)[t - NM4];
    ushort4 o;
    o.x = sk_f2bf(v.x); o.y = sk_f2bf(v.y); o.z = sk_f2bf(v.z); o.w = sk_f2bf(v.w);
    ((ushort4*)Db)[t] = o;
    if (t < N_PTS) { lw[t] = __log2f(h[t]); r32[t] = 0x7fffffff; }
    else if (t < NM_PTS) {
        const float w2 = __log2f(hi[t - N_PTS]);
        lw[t] = w2; hbF[t - N_PTS] = w2;
    }
}

// ---------------------------------------------------------------------------
// MFMA bf16 NT-GEMM, 128x128 tile, 256 thr, k+1 register prefetch.
// MODE 0: Xb[gm,gn] = bf16(dot) via LDS-transpose epilogue.
// MODE 1: q = sat_u16(relu(xs+ys-dot)*12800); writes column-packed
//         QTu16[gn,gm] + per-row atomicMin into R32.
// ---------------------------------------------------------------------------
template<int MODE>
__global__ __launch_bounds__(256) void sk_mfma(
    const unsigned short* __restrict__ A, const unsigned short* __restrict__ B,
    unsigned short* __restrict__ Xb,
    unsigned short* __restrict__ QT, int* __restrict__ R32,
    const float* __restrict__ xs, const float* __restrict__ ys)
{
    constexpr int LS = 40;
    __shared__ unsigned short As[128 * LS];
    __shared__ unsigned short Bs[128 * LS];
    __shared__ int rmin[128];
    const int tid  = threadIdx.x;
    const int wave = tid >> 6, lane = tid & 63;
    const int quad = lane >> 4, l16 = lane & 15;
    const int row0 = blockIdx.y * 128, col0 = blockIdx.x * 128;
    const int wr = (wave >> 1) * 64, wc = (wave & 1) * 64;
    if (MODE == 1 && tid < 128) rmin[tid] = 0x7fffffff;

    const int sr = tid >> 2;
    const int sk = (tid & 3) * 8;
    const unsigned short* Ap  = A + (size_t)(row0 + sr) * D_DIM + sk;
    const unsigned short* Ap2 = Ap + (size_t)64 * D_DIM;
    const unsigned short* Bp  = B + (size_t)(col0 + sr) * D_DIM + sk;
    const unsigned short* Bp2 = Bp + (size_t)64 * D_DIM;

    f32x4 acc[4][4] = {};

    short8 a0 = *(const short8*)(Ap);
    short8 a1 = *(const short8*)(Ap2);
    short8 b0 = *(const short8*)(Bp);
    short8 b1 = *(const short8*)(Bp2);

    for (int k0 = 0; k0 < D_DIM; k0 += 32) {
        __syncthreads();
        *(short8*)(As + sr * LS + sk)        = a0;
        *(short8*)(As + (sr + 64) * LS + sk) = a1;
        *(short8*)(Bs + sr * LS + sk)        = b0;
        *(short8*)(Bs + (sr + 64) * LS + sk) = b1;
        const int kn = (k0 + 32 < D_DIM) ? k0 + 32 : 0;  // last iter: dummy (hot)
        a0 = *(const short8*)(Ap + kn);
        a1 = *(const short8*)(Ap2 + kn);
        b0 = *(const short8*)(Bp + kn);
        b1 = *(const short8*)(Bp2 + kn);
        __syncthreads();
        short8 af[4], bfr[4];
        #pragma unroll
        for (int i = 0; i < 4; ++i) {
            af[i]  = *(const short8*)(As + (wr + i * 16 + l16) * LS + quad * 8);
            bfr[i] = *(const short8*)(Bs + (wc + i * 16 + l16) * LS + quad * 8);
        }
        #pragma unroll
        for (int i = 0; i < 4; ++i)
            #pragma unroll
            for (int j = 0; j < 4; ++j)
                acc[i][j] = __builtin_amdgcn_mfma_f32_16x16x32_bf16(
                    af[i], bfr[j], acc[i][j], 0, 0, 0);
    }

    if (MODE == 0) {
        unsigned short* sl = As;
        const int sgrp = wr >> 6;
        const int osg = tid >> 7, orow = (tid >> 3) & 15, oc16 = (tid & 7) * 16;
        #pragma unroll
        for (int i = 0; i < 4; ++i) {
            __syncthreads();
            #pragma unroll
            for (int j = 0; j < 4; ++j)
                #pragma unroll
                for (int r = 0; r < 4; ++r)
                    sl[sgrp * 2176 + (quad * 4 + r) * 136 + wc + j * 16 + l16] =
                        sk_f2bf(acc[i][j][r]);
            __syncthreads();
            const unsigned short* src = sl + osg * 2176 + orow * 136 + oc16;
            const short8 v0 = *(const short8*)src;
            const short8 v1 = *(const short8*)(src + 8);
            unsigned short* dst = Xb +
                (size_t)(row0 + osg * 64 + i * 16 + orow) * D_DIM + col0 + oc16;
            *(short8*)dst = v0;
            *(short8*)(dst + 8) = v1;
        }
    } else {
        const int gm0 = row0 + wr + quad * 4;
        const int gn0 = col0 + wc + l16;
        #pragma unroll
        for (int i = 0; i < 4; ++i) {
            float xv[4];
            #pragma unroll
            for (int r = 0; r < 4; ++r) xv[r] = xs[gm0 + i * 16 + r];
            int qmn[4] = {0x7fffffff, 0x7fffffff, 0x7fffffff, 0x7fffffff};
            #pragma unroll
            for (int j = 0; j < 4; ++j) {
                const int gn = gn0 + j * 16;
                const float ysv = ys[gn];
                int iq[4];
                #pragma unroll
                for (int r = 0; r < 4; ++r) {
                    const float c = fmaxf(xv[r] + ysv - acc[i][j][r], 0.f);
                    iq[r] = (int)fminf(fmaf(c, QSCALE_F, 0.5f), 65535.f);
                    qmn[r] = min(qmn[r], iq[r]);
                }
                *(ushort4*)(QT + (size_t)gn * N_PTS + gm0 + i * 16) =
                    make_ushort4((unsigned short)iq[0], (unsigned short)iq[1],
                                 (unsigned short)iq[2], (unsigned short)iq[3]);
            }
            #pragma unroll
            for (int r = 0; r < 4; ++r)
                atomicMin(&rmin[wr + i * 16 + quad * 4 + r], qmn[r]);
        }
        __syncthreads();
        if (tid < 128) atomicMin(&R32[row0 + tid], rmin[tid]);
    }
}

// ---------------------------------------------------------------------------
// xs[r] = 0.5*||Xb[r,:]||^2 from bf16
// ---------------------------------------------------------------------------
__global__ __launch_bounds__(256) void sk_row_norms(
    const unsigned short* __restrict__ Xb, float* __restrict__ XS)
{
    const int row  = blockIdx.x * 4 + (threadIdx.x >> 6);
    const int lane = threadIdx.x & 63;
    const unsigned int* p = (const unsigned int*)(Xb + (size_t)row * D_DIM);
    float s = 0.f;
    #pragma unroll
    for (int k = 0; k < 6; ++k) {
        const unsigned int u = p[lane + k * 64];
        const float f0 = __uint_as_float(u << 16);
        const float f1 = __uint_as_float(u & 0xffff0000u);
        s = fmaf(f0, f0, s); s = fmaf(f1, f1, s);
    }
    #pragma unroll
    for (int off = 32; off; off >>= 1) s += __shfl_xor(s, off, 64);
    if (lane == 0) XS[row] = 0.5f * s;
}

// ---------------------------------------------------------------------------
// Fused transpose+quant: QTu16 [2048 x 8192] -> Q8 (PERMUTED rows, i-major)
// AND QT8 (PERMUTED per-seg rows, j-major), reading QTu exactly once.
// ---------------------------------------------------------------------------
__global__ __launch_bounds__(256) void sk_transq(
    const unsigned short* __restrict__ QT, const int* __restrict__ R32,
    unsigned char* __restrict__ Q8, unsigned char* __restrict__ QT8)
{
    __shared__ unsigned short tile[64][72];
    __shared__ int rs[64];
    const int tid = threadIdx.x;
    const int J0 = blockIdx.x * 64;   // logical j (cols of Q8, rows of QT8)
    const int I0 = blockIdx.y * 64;   // i (rows of Q8, cols of QT8)
    const int tj = tid >> 2, ti = (tid & 3) * 16;
    const uint4* src = (const uint4*)(QT + (size_t)(J0 + tj) * N_PTS + I0 + ti);
    const uint4 a = src[0], b = src[1];
    *(uint4*)&tile[tj][ti] = a;
    *(uint4*)&tile[tj][ti + 8] = b;
    if (tid < 64) rs[tid] = R32[I0 + tid];
    __syncthreads();
    {
        const unsigned int qs[8] = {a.x, a.y, a.z, a.w, b.x, b.y, b.z, b.w};
        const int s  = I0 >> 11;
        const int ip = I0 & 2047;
        const int t  = ip >> 8;
        const int L0 = ((ip >> 2) & 63) + (ti >> 2);
        unsigned char* orow = QT8 + (size_t)(J0 + tj) * N_PTS + 2048 * s + 4 * t;
        #pragma unroll
        for (int q = 0; q < 4; ++q) {
            unsigned char ob[4];
            #pragma unroll
            for (int e = 0; e < 4; ++e) {
                const int k = q * 4 + e;
                const int qv = (int)((qs[k >> 1] >> ((k & 1) * 16)) & 0xffffu);
                ob[e] = (unsigned char)fminf(
                    fmaf((float)(qv - rs[ti + k]), 1.0f / 12.0f, 0.5f), 255.f);
            }
            *(unsigned int*)(orow + 32 * (L0 + q)) = *(const unsigned int*)ob;
        }
    }
    {
        const int li = tid >> 2, lj = (tid & 3) * 16;
        const int R = rs[li];
        const int L0 = (J0 >> 2) & 63;      // 16-aligned
        const int t0 = J0 >> 8;
        unsigned char* orow = Q8 + (size_t)(I0 + li) * M_PTS;
        #pragma unroll
        for (int q = 0; q < 4; ++q) {
            unsigned char ob[4];
            #pragma unroll
            for (int e = 0; e < 4; ++e) {
                const int qv = (int)tile[lj + q * 4 + e][li];
                ob[e] = (unsigned char)fminf(
                    fmaf((float)(qv - R), 1.0f / 12.0f, 0.5f), 255.f);
            }
            *(unsigned int*)(orow + 32 * (L0 + (lj >> 2) + q) + 4 * t0) =
                *(const unsigned int*)ob;
        }
    }
}

// ---------------------------------------------------------------------------
// F softmin over permuted Q8 rows (2048 cols). 2 rows/wave, 16 rows/block,
// 512 thr, 512 blocks. Bias registers loaded once, reused for both rows.
// non-final: hbG[i] = la2[i] - LSE2 ; final: FO[i] = eps*(R_i*u16nat - ln2*LSE2)
// ---------------------------------------------------------------------------
template<bool FINAL>
__global__ __launch_bounds__(512) void sk_smF(
    const unsigned char* __restrict__ Q8, const float* __restrict__ hbF,
    const float* __restrict__ LW, const int* __restrict__ R32,
    float* __restrict__ outv)
{
    const int tid = threadIdx.x, wave = tid >> 6, lane = tid & 63;
    const int frow0 = (blockIdx.x * 8 + wave) * 2;
    const uint4* qp0 = (const uint4*)(Q8 + (size_t)frow0 * M_PTS);
    const uint4* qp1 = (const uint4*)(Q8 + (size_t)(frow0 + 1) * M_PTS);
    const uint4 q00 = qp0[lane * 2], q01 = qp0[lane * 2 + 1];
    const uint4 q10 = qp1[lane * 2], q11 = qp1[lane * 2 + 1];
    float hbr[32];
    const float4* hb4 = (const float4*)hbF;
    #pragma unroll
    for (int t = 0; t < 8; ++t) {
        const float4 v = hb4[t * 64 + lane];
        hbr[t * 4 + 0] = v.x; hbr[t * 4 + 1] = v.y;
        hbr[t * 4 + 2] = v.z; hbr[t * 4 + 3] = v.w;
    }
    float m, s;
    sk_wave_ms(q00, q01, hbr, m, s);
    if (lane == 0) {
        const float lse2 = m + __log2f(s);
        if (FINAL) outv[frow0] = EPS_F * ((float)R32[frow0] * U16_TO_NAT - LN2_F * lse2);
        else       outv[frow0] = LW[frow0] - lse2;
    }
    sk_wave_ms(q10, q11, hbr, m, s);
    if (lane == 0) {
        const float lse2 = m + __log2f(s);
        if (FINAL) outv[frow0 + 1] =
            EPS_F * ((float)R32[frow0 + 1] * U16_TO_NAT - LN2_F * lse2);
        else       outv[frow0 + 1] = LW[frow0 + 1] - lse2;
    }
}

// ---------------------------------------------------------------------------
// G softmin over permuted QT8 rows (8192 cols = 4 segments). 4 rows/block,
// 512 thr: wave (seg=wave&3, rl=wave>>2) handles rows base+rl and base+2+rl
// on segment seg (bias slice loaded once, reused). 16-entry LDS merge.
// writes hbF[j] = lb2[j] - LSE2
// ---------------------------------------------------------------------------
__global__ __launch_bounds__(512) void sk_smG(
    const unsigned char* __restrict__ QT8, const float* __restrict__ hbG,
    const float* __restrict__ LW, float* __restrict__ hbF)
{
    __shared__ float mred[16], sred[16];
    const int tid = threadIdx.x, wave = tid >> 6, lane = tid & 63;
    const int seg = wave & 3, rl = wave >> 2;
    const int base = blockIdx.x * 4;
    const uint4* qp0 = (const uint4*)(QT8 + (size_t)(base + rl) * N_PTS + seg * 2048);
    const uint4* qp1 = (const uint4*)(QT8 + (size_t)(base + 2 + rl) * N_PTS + seg * 2048);
    const uint4 q00 = qp0[lane * 2], q01 = qp0[lane * 2 + 1];
    const uint4 q10 = qp1[lane * 2], q11 = qp1[lane * 2 + 1];
    const float4* hb4 = (const float4*)hbG;
    float hbr[32];
    #pragma unroll
    for (int t = 0; t < 8; ++t) {
        const float4 v = hb4[seg * 512 + t * 64 + lane];
        hbr[t * 4 + 0] = v.x; hbr[t * 4 + 1] = v.y;
        hbr[t * 4 + 2] = v.z; hbr[t * 4 + 3] = v.w;
    }
    float m, s;
    sk_wave_ms(q00, q01, hbr, m, s);
    if (lane == 0) { mred[wave] = m; sred[wave] = s; }
    sk_wave_ms(q10, q11, hbr, m, s);
    if (lane == 0) { mred[8 + wave] = m; sred[8 + wave] = s; }
    __syncthreads();
    if (tid < 4) {
        const int p = tid >> 1, r2 = tid & 1;   // p: row-pass (0:+rl, 1:+2+rl)
        const int b = p * 8 + r2 * 4;
        const float M = fmaxf(fmaxf(mred[b], mred[b + 1]),
                              fmaxf(mred[b + 2], mred[b + 3]));
        float S = 0.f;
        #pragma unroll
        for (int k = 0; k < 4; ++k)
            S += sred[b + k] * __builtin_amdgcn_exp2f(mred[b + k] - M);
        const int row = base + p * 2 + r2;
        hbF[row] = LW[N_PTS + row] - (M + __log2f(S));
    }
}

// ---------------------------------------------------------------------------
// S = <h, FO + eps*ln2*la2/2> + <hi, eps*ln2*(hbF2 - lb2/2)>; out = exp(-S)
// ---------------------------------------------------------------------------
__global__ __launch_bounds__(1024) void sk_finalize(
    const float* __restrict__ fo, const float* __restrict__ hbF,
    const float* __restrict__ h, const float* __restrict__ hi,
    const float* __restrict__ lw, float* __restrict__ out)
{
    const int tid = threadIdx.x;
    float acc = 0.f;
    for (int r = tid; r < N_PTS; r += 1024)
        acc += h[r] * (fo[r] + 0.5f * EPS_F * LN2_F * lw[r]);
    for (int j = tid; j < M_PTS; j += 1024)
        acc += hi[j] * (EPS_F * LN2_F) * (hbF[j] - 0.5f * lw[N_PTS + j]);
    #pragma unroll
    for (int off = 1; off < 64; off <<= 1) acc += __shfl_xor(acc, off, 64);
    __shared__ float red[16];
    if ((tid & 63) == 0) red[tid >> 6] = acc;
    __syncthreads();
    if (tid < 16) {
        float v = red[tid];
        #pragma unroll
        for (int off = 1; off < 16; off <<= 1) v += __shfl_xor(v, off, 16);
        if (tid == 0) out[0] = expf(-v);
    }
}

// ---------------------------------------------------------------------------
extern "C" void kernel_launch(void* const* d_in, const int* in_sizes, int n_in,
                              void* d_out, int out_size, void* d_ws, size_t ws_size,
                              hipStream_t stream)
{
    const float* dpts = (const float*)d_in[0];
    const float* spts = (const float*)d_in[1];
    const float* h    = (const float*)d_in[2];
    const float* hiw  = (const float*)d_in[3];
    const float* W    = (const float*)d_in[4];
    float* out = (float*)d_out;

    float* XS  = (float*)d_ws;                        // NM
    float* LW  = XS + NM_PTS;                         // NM (la2 | lb2), log2 dom
    float* HBF = LW + NM_PTS;                         // M  (log2 dom)
    float* HBG = HBF + M_PTS;                         // N  (log2 dom)
    float* FO  = HBG + N_PTS;                         // N  (nat dom)
    int*   R32 = (int*)(FO + N_PTS);                  // N
    unsigned short* Db = (unsigned short*)(R32 + N_PTS);        // NM x D bf16
    unsigned short* Wb = Db + (size_t)NM_PTS * D_DIM;           // D x D bf16
    unsigned short* Xb = Wb + (size_t)D_DIM * D_DIM;            // NM x D bf16
    unsigned short* QTu = Xb + (size_t)NM_PTS * D_DIM;          // M x N u16
    unsigned char*  Q8  = (unsigned char*)(QTu + (size_t)M_PTS * N_PTS); // N x M u8
    unsigned char*  QT8 = Q8 + (size_t)N_PTS * M_PTS;           // M x N u8

    // merged init + 3 casts (Wb is contiguous after Db: one dst stream)
    sk_prep<<<(NM_PTS * D_DIM + D_DIM * D_DIM) / 1024, 256, 0, stream>>>(
        dpts, spts, W, h, hiw, Db, LW, HBF, R32);

    sk_mfma<0><<<dim3(D_DIM / 128, NM_PTS / 128), 256, 0, stream>>>(
        Db, Wb, Xb, nullptr, nullptr, nullptr, nullptr);

    sk_row_norms<<<NM_PTS / 4, 256, 0, stream>>>(Xb, XS);

    sk_mfma<1><<<dim3(M_PTS / 128, N_PTS / 128), 256, 0, stream>>>(
        Xb, Xb + (size_t)N_PTS * D_DIM, nullptr, QTu, R32, XS, XS + N_PTS);

    sk_transq<<<dim3(M_PTS / 64, N_PTS / 64), 256, 0, stream>>>(QTu, R32, Q8, QT8);

    for (int it = 0; it < SINK_ITERS; ++it) {
        sk_smF<false><<<N_PTS / 16, 512, 0, stream>>>(Q8, HBF, LW, R32, HBG);
        sk_smG       <<<M_PTS / 4, 512, 0, stream>>>(QT8, HBG, LW, HBF);
    }
    sk_smF<true><<<N_PTS / 16, 512, 0, stream>>>(Q8, HBF, LW, R32, FO);

    sk_finalize<<<1, 1024, 0, stream>>>(FO, HBF, h, hiw, LW, out);
}